// Round 2
// baseline (11234.595 us; speedup 1.0000x reference)
//
#include <hip/hip_runtime.h>
#include <math.h>

#define BB   128
#define PP   256
#define PIX_ 256
#define DD   512
#define CC   10
#define MTOT (BB*PP)   // 32768

static constexpr float SCALE_F = 0.35355339059327373f; // 8/sqrt(512)
static constexpr float PI_F    = 3.14159265358979323846f;

// ---------------- setup: rotation tables, freq table, flags ----------------
__global__ void k_setup(const float* __restrict__ q_rot, const float* __restrict__ k_rot,
                        const float* __restrict__ v_rot,
                        float* __restrict__ freq, float* __restrict__ cd, float* __restrict__ sd,
                        float* __restrict__ cv, float* __restrict__ sv,
                        float* __restrict__ accum, int* __restrict__ active) {
    int t = threadIdx.x;
    if (t < DD) {
        freq[t] = expf(-(float)t * (9.210340371976184f / 512.0f)); // 10000^(-d/512)
        float dl = q_rot[t] - k_rot[t];
        cd[t] = cosf(dl);       sd[t] = sinf(dl);
        cv[t] = cosf(v_rot[t]); sv[t] = sinf(v_rot[t]);
    }
    if (t == 0) { accum[0] = 0.f; accum[1] = 0.f; *active = 1; }
}

#define SCAT4(TILE, V4) do { TILE[lk+0][lrow]=(V4).x; TILE[lk+1][lrow]=(V4).y; \
                             TILE[lk+2][lrow]=(V4).z; TILE[lk+3][lrow]=(V4).w; } while(0)

// ---------------- init: state = tanh(x@Wp^T + bp) * e^{i*p*freq*pi} ----------------
// NT GEMM: M=32768 (b*P+p), N=512 (d), K=256 (pix)
__global__ __launch_bounds__(256) void k_init(const float* __restrict__ x,
        const float* __restrict__ Wp, const float* __restrict__ bp,
        const float* __restrict__ freq,
        float* __restrict__ Sr, float* __restrict__ Si) {
    __shared__ float As[16][68];
    __shared__ float Bs[16][68];
    const int bm = blockIdx.y * 64, bn = blockIdx.x * 64;
    const int t = threadIdx.x, tx = t & 15, ty = t >> 4;
    const int lrow = t >> 2, lk = (t & 3) * 4;
    float acc[4][4] = {};
    for (int k0 = 0; k0 < PIX_; k0 += 16) {
        const float4 a4 = *(const float4*)(x  + (size_t)(bm + lrow) * PIX_ + k0 + lk);
        const float4 b4 = *(const float4*)(Wp + (size_t)(bn + lrow) * PIX_ + k0 + lk);
        __syncthreads();
        SCAT4(As, a4);
        SCAT4(Bs, b4);
        __syncthreads();
#pragma unroll
        for (int kk = 0; kk < 16; ++kk) {
            const float4 av = *(const float4*)&As[kk][ty * 4];
            const float4 bv = *(const float4*)&Bs[kk][tx * 4];
            const float a[4] = {av.x, av.y, av.z, av.w};
            const float b[4] = {bv.x, bv.y, bv.z, bv.w};
#pragma unroll
            for (int i = 0; i < 4; i++)
#pragma unroll
                for (int j = 0; j < 4; j++) acc[i][j] = fmaf(a[i], b[j], acc[i][j]);
        }
    }
#pragma unroll
    for (int i = 0; i < 4; i++) {
        const int m = bm + ty * 4 + i;
        const int p = m & 255;
        float4 vr, vi;
        float* pvr = (float*)&vr; float* pvi = (float*)&vi;
#pragma unroll
        for (int j = 0; j < 4; j++) {
            const int d = bn + tx * 4 + j;
            const float mg = tanhf(acc[i][j] + bp[d]);
            const float ph = (float)p * freq[d] * PI_F;
            float sph, cph; sincosf(ph, &sph, &cph);
            pvr[j] = mg * cph; pvi[j] = mg * sph;
        }
        *(float4*)(Sr + (size_t)m * DD + bn + tx * 4) = vr;
        *(float4*)(Si + (size_t)m * DD + bn + tx * 4) = vi;
    }
}

// ---------------- scores: S[b,p,q] = scale * Re(q . conj(k)) ----------------
// per-sample NT GEMM M=N=256, K=512 x 2 planes; K rotation fused into staging.
// Sr/Si are chunk-local (C samples); A is chunk-local.
__global__ __launch_bounds__(256) void k_score(const float* __restrict__ Sr, const float* __restrict__ Si,
        const float* __restrict__ cd, const float* __restrict__ sd,
        float* __restrict__ A) {
    __shared__ float Qr[16][68], Qi[16][68], Kr[16][68], Ki[16][68];
    const int b = blockIdx.z;
    const float* sr = Sr + (size_t)b * PP * DD;
    const float* si = Si + (size_t)b * PP * DD;
    const int bm = blockIdx.y * 64, bn = blockIdx.x * 64;
    const int t = threadIdx.x, tx = t & 15, ty = t >> 4;
    const int lrow = t >> 2, lk = (t & 3) * 4;
    float acc[4][4] = {};
    for (int k0 = 0; k0 < DD; k0 += 16) {
        const float4 qr4 = *(const float4*)(sr + (size_t)(bm + lrow) * DD + k0 + lk);
        const float4 qi4 = *(const float4*)(si + (size_t)(bm + lrow) * DD + k0 + lk);
        const float4 kr4 = *(const float4*)(sr + (size_t)(bn + lrow) * DD + k0 + lk);
        const float4 ki4 = *(const float4*)(si + (size_t)(bn + lrow) * DD + k0 + lk);
        const float4 c4  = *(const float4*)(cd + k0 + lk);
        const float4 s4  = *(const float4*)(sd + k0 + lk);
        __syncthreads();
        SCAT4(Qr, qr4);
        SCAT4(Qi, qi4);
        Kr[lk+0][lrow] = kr4.x*c4.x + ki4.x*s4.x;  Ki[lk+0][lrow] = ki4.x*c4.x - kr4.x*s4.x;
        Kr[lk+1][lrow] = kr4.y*c4.y + ki4.y*s4.y;  Ki[lk+1][lrow] = ki4.y*c4.y - kr4.y*s4.y;
        Kr[lk+2][lrow] = kr4.z*c4.z + ki4.z*s4.z;  Ki[lk+2][lrow] = ki4.z*c4.z - kr4.z*s4.z;
        Kr[lk+3][lrow] = kr4.w*c4.w + ki4.w*s4.w;  Ki[lk+3][lrow] = ki4.w*c4.w - kr4.w*s4.w;
        __syncthreads();
#pragma unroll
        for (int kk = 0; kk < 16; ++kk) {
            const float4 arv = *(const float4*)&Qr[kk][ty * 4];
            const float4 aiv = *(const float4*)&Qi[kk][ty * 4];
            const float4 brv = *(const float4*)&Kr[kk][tx * 4];
            const float4 biv = *(const float4*)&Ki[kk][tx * 4];
            const float ar[4] = {arv.x, arv.y, arv.z, arv.w};
            const float ai[4] = {aiv.x, aiv.y, aiv.z, aiv.w};
            const float br_[4] = {brv.x, brv.y, brv.z, brv.w};
            const float bi_[4] = {biv.x, biv.y, biv.z, biv.w};
#pragma unroll
            for (int i = 0; i < 4; i++)
#pragma unroll
                for (int j = 0; j < 4; j++)
                    acc[i][j] += ar[i] * br_[j] + ai[i] * bi_[j];
        }
    }
    float* Ab = A + (size_t)b * PP * PP;
#pragma unroll
    for (int i = 0; i < 4; i++) {
        float4 v = make_float4(acc[i][0]*SCALE_F, acc[i][1]*SCALE_F, acc[i][2]*SCALE_F, acc[i][3]*SCALE_F);
        *(float4*)(Ab + (size_t)(bm + ty * 4 + i) * PP + bn + tx * 4) = v;
    }
}

// ---------------- softmax over rows of length 256, one wave per row ----------------
__global__ __launch_bounds__(256) void k_softmax(float* __restrict__ A) {
    const int row = blockIdx.x * 4 + (threadIdx.x >> 6);
    const int lane = threadIdx.x & 63;
    float* a = A + (size_t)row * PP;
    float v[4];
#pragma unroll
    for (int k = 0; k < 4; k++) v[k] = a[lane + 64 * k];
    float m = fmaxf(fmaxf(v[0], v[1]), fmaxf(v[2], v[3]));
#pragma unroll
    for (int off = 32; off; off >>= 1) m = fmaxf(m, __shfl_xor(m, off, 64));
    float s = 0.f;
#pragma unroll
    for (int k = 0; k < 4; k++) { v[k] = expf(v[k] - m); s += v[k]; }
#pragma unroll
    for (int off = 32; off; off >>= 1) s += __shfl_xor(s, off, 64);
    const float inv = 1.0f / s;
#pragma unroll
    for (int k = 0; k < 4; k++) a[lane + 64 * k] = v[k] * inv;
}

// ---------------- attn_out: T = prev + (A @ state) * e^{i v_rot} ----------------
// per-sample NN GEMM: M=256(p), N=512(d), K=256(q); A real, state complex.
__global__ __launch_bounds__(256) void k_attnout(const float* __restrict__ A,
        const float* __restrict__ Sr, const float* __restrict__ Si,
        const float* __restrict__ cv, const float* __restrict__ sv,
        float* __restrict__ Tr, float* __restrict__ Ti) {
    __shared__ float As[16][68], Br[16][68], Bi[16][68];
    const int b = blockIdx.z;
    const int bm = blockIdx.y * 64, bn = blockIdx.x * 64;
    const int t = threadIdx.x, tx = t & 15, ty = t >> 4;
    const int lrow = t >> 2, lk = (t & 3) * 4;
    const int bkk = t >> 4, bn4 = (t & 15) * 4;
    const float* Ab = A + (size_t)b * PP * PP;
    const float* sr = Sr + (size_t)b * PP * DD;
    const float* si = Si + (size_t)b * PP * DD;
    float accr[4][4] = {}, acci[4][4] = {};
    for (int k0 = 0; k0 < PP; k0 += 16) {
        const float4 a4  = *(const float4*)(Ab + (size_t)(bm + lrow) * PP + k0 + lk);
        const float4 br4 = *(const float4*)(sr + (size_t)(k0 + bkk) * DD + bn + bn4);
        const float4 bi4 = *(const float4*)(si + (size_t)(k0 + bkk) * DD + bn + bn4);
        __syncthreads();
        SCAT4(As, a4);
        *(float4*)&Br[bkk][bn4] = br4;
        *(float4*)&Bi[bkk][bn4] = bi4;
        __syncthreads();
#pragma unroll
        for (int kk = 0; kk < 16; ++kk) {
            const float4 av  = *(const float4*)&As[kk][ty * 4];
            const float4 brv = *(const float4*)&Br[kk][tx * 4];
            const float4 biv = *(const float4*)&Bi[kk][tx * 4];
            const float a[4]   = {av.x, av.y, av.z, av.w};
            const float br_[4] = {brv.x, brv.y, brv.z, brv.w};
            const float bi_[4] = {biv.x, biv.y, biv.z, biv.w};
#pragma unroll
            for (int i = 0; i < 4; i++)
#pragma unroll
                for (int j = 0; j < 4; j++) {
                    accr[i][j] = fmaf(a[i], br_[j], accr[i][j]);
                    acci[i][j] = fmaf(a[i], bi_[j], acci[i][j]);
                }
        }
    }
#pragma unroll
    for (int i = 0; i < 4; i++) {
        const int p = bm + ty * 4 + i;
        float4 vr, vi;
        float* pvr = (float*)&vr; float* pvi = (float*)&vi;
#pragma unroll
        for (int j = 0; j < 4; j++) {
            const int d = bn + tx * 4 + j;
            const float cvd = cv[d], svd = sv[d];
            const float wr = accr[i][j], wi = acci[i][j];
            const float aor = wr * cvd - wi * svd;
            const float aoi = wr * svd + wi * cvd;
            pvr[j] = sr[(size_t)p * DD + d] + aor;
            pvi[j] = si[(size_t)p * DD + d] + aoi;
        }
        const size_t idx = ((size_t)b * PP + p) * DD + bn + tx * 4;
        *(float4*)(Tr + idx) = vr;
        *(float4*)(Ti + idx) = vi;
    }
}

// ---------------- ff: U = T @ (ff_real + i ff_imag) ----------------
// NN complex GEMM: M=C*256, N=512, K=512.
__global__ __launch_bounds__(256) void k_ff(const float* __restrict__ Tr, const float* __restrict__ Ti,
        const float* __restrict__ Fr, const float* __restrict__ Fi,
        float* __restrict__ Ur, float* __restrict__ Ui) {
    __shared__ float Ar[16][68], Ai[16][68], Br[16][68], Bi[16][68];
    const int bm = blockIdx.y * 64, bn = blockIdx.x * 64;
    const int t = threadIdx.x, tx = t & 15, ty = t >> 4;
    const int lrow = t >> 2, lk = (t & 3) * 4;
    const int bkk = t >> 4, bn4 = (t & 15) * 4;
    float accr[4][4] = {}, acci[4][4] = {};
    for (int k0 = 0; k0 < DD; k0 += 16) {
        const float4 ar4 = *(const float4*)(Tr + (size_t)(bm + lrow) * DD + k0 + lk);
        const float4 ai4 = *(const float4*)(Ti + (size_t)(bm + lrow) * DD + k0 + lk);
        const float4 br4 = *(const float4*)(Fr + (size_t)(k0 + bkk) * DD + bn + bn4);
        const float4 bi4 = *(const float4*)(Fi + (size_t)(k0 + bkk) * DD + bn + bn4);
        __syncthreads();
        SCAT4(Ar, ar4);
        SCAT4(Ai, ai4);
        *(float4*)&Br[bkk][bn4] = br4;
        *(float4*)&Bi[bkk][bn4] = bi4;
        __syncthreads();
#pragma unroll
        for (int kk = 0; kk < 16; ++kk) {
            const float4 arv = *(const float4*)&Ar[kk][ty * 4];
            const float4 aiv = *(const float4*)&Ai[kk][ty * 4];
            const float4 brv = *(const float4*)&Br[kk][tx * 4];
            const float4 biv = *(const float4*)&Bi[kk][tx * 4];
            const float ar[4]  = {arv.x, arv.y, arv.z, arv.w};
            const float ai_[4] = {aiv.x, aiv.y, aiv.z, aiv.w};
            const float br_[4] = {brv.x, brv.y, brv.z, brv.w};
            const float bi_[4] = {biv.x, biv.y, biv.z, biv.w};
#pragma unroll
            for (int i = 0; i < 4; i++)
#pragma unroll
                for (int j = 0; j < 4; j++) {
                    accr[i][j] += ar[i] * br_[j] - ai_[i] * bi_[j];
                    acci[i][j] += ar[i] * bi_[j] + ai_[i] * br_[j];
                }
        }
    }
#pragma unroll
    for (int i = 0; i < 4; i++) {
        const size_t idx = (size_t)(bm + ty * 4 + i) * DD + bn + tx * 4;
        *(float4*)(Ur + idx) = make_float4(accr[i][0], accr[i][1], accr[i][2], accr[i][3]);
        *(float4*)(Ui + idx) = make_float4(acci[i][0], acci[i][1], acci[i][2], acci[i][3]);
    }
}

// ---------------- complex_norm + conditional commit + diff accumulation ----------------
// one block per row (chunk-local); D=512, 2 elems/thread. Commits S <- new iff *active.
__global__ __launch_bounds__(256) void k_norm(const float* __restrict__ Ur, const float* __restrict__ Ui,
        float* __restrict__ Sr, float* __restrict__ Si,
        float* __restrict__ accum, const int* __restrict__ active) {
    __shared__ float red[256];
    const size_t base = (size_t)blockIdx.x * DD;
    const int t = threadIdx.x;
    const int act = *active;
    const float ur0 = Ur[base + t],       ui0 = Ui[base + t];
    const float ur1 = Ur[base + t + 256], ui1 = Ui[base + t + 256];
    const float m0 = sqrtf(ur0 * ur0 + ui0 * ui0);
    const float m1 = sqrtf(ur1 * ur1 + ui1 * ui1);
    red[t] = m0 + m1;
    __syncthreads();
    for (int s = 128; s > 0; s >>= 1) { if (t < s) red[t] += red[t + s]; __syncthreads(); }
    const float mean = red[0] * (1.0f / 512.0f);
    __syncthreads();
    const float d0 = m0 - mean, d1 = m1 - mean;
    red[t] = d0 * d0 + d1 * d1;
    __syncthreads();
    for (int s = 128; s > 0; s >>= 1) { if (t < s) red[t] += red[t + s]; __syncthreads(); }
    const float stdv = sqrtf(red[0] * (1.0f / 511.0f));
    __syncthreads();
    const float sc0 = tanhf(d0 / (stdv + 1e-5f)) / (m0 + 1e-5f);
    const float sc1 = tanhf(d1 / (stdv + 1e-5f)) / (m1 + 1e-5f);
    const float nr0 = ur0 * sc0, ni0 = ui0 * sc0;
    const float nr1 = ur1 * sc1, ni1 = ui1 * sc1;
    const float pr0 = Sr[base + t],       pi0 = Si[base + t];
    const float pr1 = Sr[base + t + 256], pi1 = Si[base + t + 256];
    const float dd = (nr0-pr0)*(nr0-pr0) + (ni0-pi0)*(ni0-pi0)
                   + (nr1-pr1)*(nr1-pr1) + (ni1-pi1)*(ni1-pi1);
    const float nn = nr0*nr0 + ni0*ni0 + nr1*nr1 + ni1*ni1;
    if (act) {
        Sr[base + t] = nr0;       Si[base + t] = ni0;
        Sr[base + t + 256] = nr1; Si[base + t + 256] = ni1;
    }
    red[t] = dd;
    __syncthreads();
    for (int s = 128; s > 0; s >>= 1) { if (t < s) red[t] += red[t + s]; __syncthreads(); }
    const float ddb = red[0];
    __syncthreads();
    red[t] = nn;
    __syncthreads();
    for (int s = 128; s > 0; s >>= 1) { if (t < s) red[t] += red[t + s]; __syncthreads(); }
    if (t == 0) { atomicAdd(&accum[0], ddb); atomicAdd(&accum[1], red[0]); }
}

// ---------------- convergence flag update ----------------
__global__ void k_flag(float* __restrict__ accum, int* __restrict__ active) {
    const float diff = sqrtf(accum[0]) / (sqrtf(accum[1]) + 1e-8f);
    const int a = *active;
    *active = (a && (diff >= 1e-3f)) ? 1 : 0;
    accum[0] = 0.f; accum[1] = 0.f;
}

// ---------------- mean over P ----------------
__global__ __launch_bounds__(256) void k_pool(const float* __restrict__ Sr, const float* __restrict__ Si,
        float* __restrict__ Pr, float* __restrict__ Pi) {
    const int gid = blockIdx.x * 256 + threadIdx.x; // [0, B*D)
    const int b = gid >> 9, d = gid & 511;
    const size_t base = (size_t)b * PP * DD + d;
    float sr = 0.f, si = 0.f;
    for (int p = 0; p < PP; p++) {
        sr += Sr[base + (size_t)p * DD];
        si += Si[base + (size_t)p * DD];
    }
    Pr[gid] = sr * (1.0f / 256.0f);
    Pi[gid] = si * (1.0f / 256.0f);
}

// ---------------- logits ----------------
__global__ __launch_bounds__(64) void k_logits(const float* __restrict__ Pr, const float* __restrict__ Pi,
        const float* __restrict__ Wr, const float* __restrict__ br,
        const float* __restrict__ Wi, const float* __restrict__ bi,
        float* __restrict__ out) {
    const int b = blockIdx.x;
    const int lane = threadIdx.x;
    for (int c = 0; c < CC; c++) {
        float acc = 0.f;
#pragma unroll
        for (int k = 0; k < 8; k++) {
            const int d = lane + 64 * k;
            acc += Pr[b * DD + d] * Wr[c * DD + d] + Pi[b * DD + d] * Wi[c * DD + d];
        }
#pragma unroll
        for (int off = 32; off; off >>= 1) acc += __shfl_xor(acc, off, 64);
        if (lane == 0) out[b * CC + c] = acc + br[c] + bi[c];
    }
}

extern "C" void kernel_launch(void* const* d_in, const int* in_sizes, int n_in,
                              void* d_out, int out_size, void* d_ws, size_t ws_size,
                              hipStream_t stream) {
    const float* x     = (const float*)d_in[0];
    const float* Wp    = (const float*)d_in[1];
    const float* bp    = (const float*)d_in[2];
    const float* q_rot = (const float*)d_in[3];
    const float* k_rot = (const float*)d_in[4];
    const float* v_rot = (const float*)d_in[5];
    const float* ffr   = (const float*)d_in[6];
    const float* ffi   = (const float*)d_in[7];
    const float* Wr    = (const float*)d_in[8];
    const float* br    = (const float*)d_in[9];
    const float* Wi    = (const float*)d_in[10];
    const float* bi    = (const float*)d_in[11];
    float* out = (float*)d_out;

    float* ws = (float*)d_ws;
    const size_t plane = (size_t)MTOT * DD;      // 16,777,216 floats (full-batch complex plane half)
    const size_t sline = (size_t)PP * DD;        // 131,072 floats per sample per component

    // small-tables region: fixed 135168 floats
    float* freq = ws;                  // 512
    float* cd   = freq + DD;           // 512
    float* sd   = cd + DD;             // 512
    float* cv   = sd + DD;             // 512
    float* sv   = cv + DD;             // 512
    float* accum = sv + DD;            // 2
    int*   active = (int*)(accum + 2); // 1
    float* Pr = ws + 4096;             // 65536
    float* Pi = Pr + (size_t)BB * DD;  // 65536
    float* Sr = ws + 135168;           // persistent state
    float* Si = Sr + plane;

    // adaptive chunk size: fixed part + 4*C*sline floats must fit in ws_size
    const size_t fixed_f = 135168 + 2 * plane;
    int C = BB;
    while (C > 1 && (fixed_f + 4ull * (size_t)C * sline) * 4ull > ws_size) C >>= 1;

    float* Tr = Si + plane;                 // C*sline
    float* Ti = Tr + (size_t)C * sline;     // C*sline
    float* Ur = Ti + (size_t)C * sline;     // C*sline (Asc overlaid at its start: C*65536 <= C*sline)
    float* Ui = Ur + (size_t)C * sline;     // C*sline
    float* Asc = Ur;                        // scores, dead before k_ff writes Ur

    k_setup<<<1, 512, 0, stream>>>(q_rot, k_rot, v_rot, freq, cd, sd, cv, sv, accum, active);
    k_init<<<dim3(DD / 64, MTOT / 64), 256, 0, stream>>>(x, Wp, bp, freq, Sr, Si);

    for (int it = 0; it < 4; ++it) {
        for (int c0 = 0; c0 < BB; c0 += C) {
            float* Sr_c = Sr + (size_t)c0 * sline;
            float* Si_c = Si + (size_t)c0 * sline;
            k_score<<<dim3(PP / 64, PP / 64, C), 256, 0, stream>>>(Sr_c, Si_c, cd, sd, Asc);
            k_softmax<<<C * PP / 4, 256, 0, stream>>>(Asc);
            k_attnout<<<dim3(DD / 64, PP / 64, C), 256, 0, stream>>>(Asc, Sr_c, Si_c, cv, sv, Tr, Ti);
            k_ff<<<dim3(DD / 64, C * PP / 64), 256, 0, stream>>>(Tr, Ti, ffr, ffi, Ur, Ui);
            k_norm<<<C * PP, 256, 0, stream>>>(Ur, Ui, Sr_c, Si_c, accum, active);
        }
        k_flag<<<1, 1, 0, stream>>>(accum, active);
    }

    k_pool<<<BB * DD / 256, 256, 0, stream>>>(Sr, Si, Pr, Pi);
    k_logits<<<BB, 64, 0, stream>>>(Pr, Pi, Wr, br, Wi, bi, out);
}